// Round 8
// baseline (602.880 us; speedup 1.0000x reference)
//
#include <hip/hip_runtime.h>
#include <hip/hip_cooperative_groups.h>

namespace cg = cooperative_groups;

#define NN 100000
#define NE 1600000
#define DD 128
#define BN_EPS 1e-5f

#define SBSH 8                         // log2(super-bucket size)
#define SBSZ 256                       // nodes per super-bucket
#define NSB ((NN + SBSZ - 1) / SBSZ)   // 391 super-buckets
#define CAPS 4608                      // slots per bucket (mean 4081 + ~8 sigma)
#define EPB 8192                       // edges per scatter segment
#define NBLK ((NE + EPB - 1) / EPB)    // 196 scatter-role blocks
#define TSZ 64                         // nodes per gather/MLP tile
#define NTILE ((NN + TSZ - 1) / TSZ)   // 1563
#define GRIDSZ 1024                    // 4 blocks/CU x 256 CU at 34.8KB LDS

typedef __attribute__((ext_vector_type(8))) short short8;
typedef __attribute__((ext_vector_type(4))) float floatx4;

__device__ __forceinline__ unsigned short f2bf(float f) {
    union { float f; unsigned u; } v; v.f = f;
    return (unsigned short)((v.u + 0x7FFFu + ((v.u >> 16) & 1u)) >> 16);
}
__device__ __forceinline__ float bf2f(unsigned short u) {
    union { unsigned u; float f; } v; v.u = ((unsigned)u) << 16;
    return v.f;
}

struct GinParams {
    const float* h; const int* src; const int* dst; const float* eps;
    const float* W1; const float* b1; const float* W2; const float* b2;
    const float* gamma; const float* beta;
    float* out;
    float* stats; int* scnt; int* ticket;
    unsigned short* W1t; unsigned short* W2t;
    int2* off2; int* sbuf; unsigned short* xb; unsigned short* hb;
};

// ---------------------------------------------------------------------------
// Mega-kernel v2 (one cooperative dispatch, 5 phases):
//  P0 : zero scnt/stats/ticket
//  PA : bid<196 -> super-bucket radix scatter (chunks ~21 edges, single-
//       writer -> write-combined, the R6 fix; R5's 21B-subline pathology
//       [WRITE_SIZE 127MB] came from skipping this);  bid>=196 -> prep
//       (W->bf16 transpose + h->bf16). bids interleave across CUs.
//  PA2: bid<391 -> per-bucket CSR permute, 18.4KB LDS stage (SBSZ=256 chosen
//       so it fits the shared arena), off2[node]={beg,end} absolute.
//  PB : R6-K3 body verbatim (gather + 2xMFMA GEMM with LDS-staged W halves +
//       BN partials), DYNAMIC TICKET over 1563 tiles (fixes R5's grid-stride
//       imbalance; balances degree variance too).
//  PC : out = h + relu(BN(Y2)).
// ---------------------------------------------------------------------------
template <bool HB>
__global__ __launch_bounds__(256, 4) void gin_mega2_kernel(GinParams p)
{
    __shared__ __align__(16) char smem[34816];
    __shared__ int tkt;

    cg::grid_group grid = cg::this_grid();
    const int t = threadIdx.x;
    const int bid = blockIdx.x;
    const int nb = gridDim.x;
    const int lane = t & 63;
    const int wv = t >> 6;
    const int m = lane & 15;
    const int hi = lane >> 4;

    // ---- P0: zero cursors/stats/ticket ----
    int gi = bid * 256 + t;
    if (gi < 512) p.scnt[gi] = 0;
    if (gi < 2 * DD) p.stats[gi] = 0.0f;
    if (gi == 0) p.ticket[0] = 0;
    grid.sync();

    // ---- PA: radix scatter (bid<196) / prep (bid>=196) ----
    if (bid < NBLK) {
        int* bins = (int*)smem;                // [512]
        for (int w = t; w < 512; w += 256) bins[w] = 0;
        __syncthreads();
        int base = bid * EPB;
        int ecnt = min(EPB, NE - base);
        for (int i = t; i < ecnt; i += 256)
            atomicAdd(&bins[p.dst[base + i] >> SBSH], 1);
        __syncthreads();
        for (int w = t; w < NSB; w += 256) {
            int c = bins[w];
            int gb = c ? atomicAdd(&p.scnt[w], c) : 0;
            bins[w] = w * CAPS + gb;           // global chunk cursor
        }
        __syncthreads();
        for (int i = t; i < ecnt; i += 256) {
            int d = p.dst[base + i];
            int pos = atomicAdd(&bins[d >> SBSH], 1);
            p.sbuf[pos] = (p.src[base + i] << SBSH) | (d & (SBSZ - 1));
        }
    } else {
        int tid0 = (bid - NBLK) * 256 + t;
        int stride = (nb - NBLK) * 256;
        for (int i = tid0; i < DD * DD; i += stride) {
            int n = i >> 7, k = i & 127;
            p.W1t[i] = f2bf(p.W1[k * DD + n]);
            p.W2t[i] = f2bf(p.W2[k * DD + n]);
        }
        if (HB) {
            const float4* h4 = (const float4*)p.h;
            ushort4* hb4 = (ushort4*)p.hb;
            for (int i = tid0; i < NN * (DD / 4); i += stride) {
                float4 v = h4[i];
                ushort4 o;
                o.x = f2bf(v.x); o.y = f2bf(v.y); o.z = f2bf(v.z); o.w = f2bf(v.w);
                hb4[i] = o;
            }
        }
    }
    grid.sync();

    // ---- PA2: per-super-bucket CSR permute (bid<391) ----
    if (bid < NSB) {
        int* ew   = (int*)smem;                // [4608] 18432B
        int* cnt  = (int*)(smem + 18432);      // [256]
        int* cur  = (int*)(smem + 19456);      // [256]
        int* stmp = (int*)(smem + 20480);      // [256]
        cnt[t] = 0;
        __syncthreads();
        int n = min(p.scnt[bid], CAPS);
        int sbase = bid * CAPS;
        for (int i = t; i < n; i += 256) {
            int e = p.sbuf[sbase + i];
            ew[i] = e;
            atomicAdd(&cnt[e & (SBSZ - 1)], 1);
        }
        __syncthreads();
        int c = cnt[t];
        stmp[t] = c;
        __syncthreads();
#pragma unroll
        for (int ofs = 1; ofs < 256; ofs <<= 1) {
            int u = (t >= ofs) ? stmp[t - ofs] : 0;
            __syncthreads();
            stmp[t] += u;
            __syncthreads();
        }
        int excl = stmp[t] - c;
        cur[t] = excl;
        p.off2[bid * SBSZ + t] = make_int2(sbase + excl, sbase + excl + c);
        __syncthreads();
        for (int i = t; i < n; i += 256) {
            int e = ew[i];
            int pos = atomicAdd(&cur[e & (SBSZ - 1)], 1);
            p.sbuf[sbase + pos] = e >> SBSH;   // in place (staged in LDS)
        }
    }
    grid.sync();

    // ---- PB: gather + MLP + BN partials, dynamic ticket over tiles ----
    {
        unsigned short* xl = (unsigned short*)smem;        // [64][136] bf16
        char* un = smem + 17408;                           // union region
        int* beg64 = (int*)un;                             // [64]
        int* cnt64 = (int*)(un + 256);                     // [64]
        int* dh    = (int*)(un + 512);                     // [64]
        int* dcur  = (int*)(un + 768);                     // [64]
        unsigned char* order = (unsigned char*)(un + 1024);// [64]
        unsigned short* wl = (unsigned short*)un;          // [64][136] W half
        float* sred = (float*)un;                          // [128][16]
        float* qred = sred + 2048;                         // [128][16]

        const float sE = 1.0f + p.eps[0];
        const float4* h4 = (const float4*)p.h;
        const short8* hb8 = (const short8*)p.hb;
        const int c8 = t & 15;

        while (true) {
            __syncthreads();   // protect previous tile's xl/sred reads
            if (t == 0) tkt = atomicAdd(p.ticket, 1);
            __syncthreads();
            int b = tkt;
            if (b >= NTILE) break;

            // per-node offsets + degree sort
            if (t < 64) dh[t] = 0;
            __syncthreads();
            if (t < 64) {
                int2 oo = p.off2[b * TSZ + t];
                beg64[t] = oo.x;
                cnt64[t] = oo.y - oo.x;
                atomicAdd(&dh[min(cnt64[t], 63)], 1);
            }
            __syncthreads();
            if (t < 64) dcur[t] = dh[t];
            __syncthreads();
#pragma unroll
            for (int ofs = 1; ofs < 64; ofs <<= 1) {
                int u = (t < 64 && t >= ofs) ? dcur[t - ofs] : 0;
                __syncthreads();
                if (t < 64) dcur[t] += u;
                __syncthreads();
            }
            if (t < 64) dcur[t] -= dh[t];
            __syncthreads();
            if (t < 64) {
                int pp = atomicAdd(&dcur[min(cnt64[t], 63)], 1);
                order[pp] = (unsigned char)t;
            }
            __syncthreads();

            // gather (16 lanes/node, degree-sorted)
#pragma unroll
            for (int pass = 0; pass < 4; ++pass) {
                int nl = order[pass * 16 + (t >> 4)];
                int node = b * TSZ + nl;
                if (node >= NN) {
                    short8 z = {0, 0, 0, 0, 0, 0, 0, 0};
                    *(short8*)&xl[nl * 136 + c8 * 8] = z;
                    continue;
                }
                float4 a0 = h4[node * 32 + c8 * 2];
                float4 a1 = h4[node * 32 + c8 * 2 + 1];
                float acc[8] = {sE * a0.x, sE * a0.y, sE * a0.z, sE * a0.w,
                                sE * a1.x, sE * a1.y, sE * a1.z, sE * a1.w};
                int e = beg64[nl], eend = beg64[nl] + cnt64[nl];
                if (HB) {
                    for (; e + 3 < eend; e += 4) {
                        int s0 = p.sbuf[e], s1 = p.sbuf[e + 1];
                        int s2 = p.sbuf[e + 2], s3 = p.sbuf[e + 3];
                        short8 v0 = hb8[s0 * 16 + c8];
                        short8 v1 = hb8[s1 * 16 + c8];
                        short8 v2 = hb8[s2 * 16 + c8];
                        short8 v3 = hb8[s3 * 16 + c8];
#pragma unroll
                        for (int j = 0; j < 8; ++j) {
                            float t0 = bf2f((unsigned short)v0[j]) + bf2f((unsigned short)v1[j]);
                            float t1 = bf2f((unsigned short)v2[j]) + bf2f((unsigned short)v3[j]);
                            acc[j] += t0 + t1;
                        }
                    }
                    for (; e < eend; ++e) {
                        short8 v0 = hb8[p.sbuf[e] * 16 + c8];
#pragma unroll
                        for (int j = 0; j < 8; ++j) acc[j] += bf2f((unsigned short)v0[j]);
                    }
                } else {
                    for (; e + 1 < eend; e += 2) {
                        int s0 = p.sbuf[e], s1 = p.sbuf[e + 1];
                        float4 u0 = h4[s0 * 32 + c8 * 2], u1 = h4[s0 * 32 + c8 * 2 + 1];
                        float4 w0 = h4[s1 * 32 + c8 * 2], w1 = h4[s1 * 32 + c8 * 2 + 1];
                        acc[0] += u0.x + w0.x; acc[1] += u0.y + w0.y;
                        acc[2] += u0.z + w0.z; acc[3] += u0.w + w0.w;
                        acc[4] += u1.x + w1.x; acc[5] += u1.y + w1.y;
                        acc[6] += u1.z + w1.z; acc[7] += u1.w + w1.w;
                    }
                    if (e < eend) {
                        int s0 = p.sbuf[e];
                        float4 u0 = h4[s0 * 32 + c8 * 2], u1 = h4[s0 * 32 + c8 * 2 + 1];
                        acc[0] += u0.x; acc[1] += u0.y; acc[2] += u0.z; acc[3] += u0.w;
                        acc[4] += u1.x; acc[5] += u1.y; acc[6] += u1.z; acc[7] += u1.w;
                    }
                }
                short8 o;
#pragma unroll
                for (int j = 0; j < 8; ++j) o[j] = (short)f2bf(acc[j]);
                *(short8*)&xl[nl * 136 + c8 * 8] = o;
            }
            __syncthreads();   // xl complete; offset scratch dead -> wl

            // GEMM1: Y1 = relu(x@W1+b1), W half-staged in LDS
            floatx4 acc[8];
#pragma unroll
            for (int i = 0; i < 8; ++i) acc[i] = (floatx4){0.f, 0.f, 0.f, 0.f};
            const short8* W1t8 = (const short8*)p.W1t;
#pragma unroll
            for (int hh = 0; hh < 2; ++hh) {
#pragma unroll
                for (int l = 0; l < 4; ++l) {
                    int idx = t + l * 256;
                    int nr = idx >> 4, c = idx & 15;
                    *(short8*)&wl[nr * 136 + c * 8] = W1t8[(hh * 64 + nr) * 16 + c];
                }
                __syncthreads();
#pragma unroll
                for (int kc = 0; kc < 4; ++kc) {
                    short8 a = *(const short8*)&xl[(wv * 16 + m) * 136 + kc * 32 + hi * 8];
#pragma unroll
                    for (int ntl = 0; ntl < 4; ++ntl) {
                        short8 bb = *(const short8*)&wl[(ntl * 16 + m) * 136 + kc * 32 + hi * 8];
                        acc[hh * 4 + ntl] =
                            __builtin_amdgcn_mfma_f32_16x16x32_bf16(a, bb, acc[hh * 4 + ntl], 0, 0, 0);
                    }
                }
                __syncthreads();
            }
#pragma unroll
            for (int nt = 0; nt < 8; ++nt) {
                float bv = p.b1[nt * 16 + m];
#pragma unroll
                for (int r = 0; r < 4; ++r) {
                    float v = fmaxf(acc[nt][r] + bv, 0.f);
                    xl[(wv * 16 + hi * 4 + r) * 136 + nt * 16 + m] = f2bf(v);
                }
            }
            __syncthreads();

            // GEMM2: Y2 = Y1@W2+b2
#pragma unroll
            for (int i = 0; i < 8; ++i) acc[i] = (floatx4){0.f, 0.f, 0.f, 0.f};
            const short8* W2t8 = (const short8*)p.W2t;
#pragma unroll
            for (int hh = 0; hh < 2; ++hh) {
#pragma unroll
                for (int l = 0; l < 4; ++l) {
                    int idx = t + l * 256;
                    int nr = idx >> 4, c = idx & 15;
                    *(short8*)&wl[nr * 136 + c * 8] = W2t8[(hh * 64 + nr) * 16 + c];
                }
                __syncthreads();
#pragma unroll
                for (int kc = 0; kc < 4; ++kc) {
                    short8 a = *(const short8*)&xl[(wv * 16 + m) * 136 + kc * 32 + hi * 8];
#pragma unroll
                    for (int ntl = 0; ntl < 4; ++ntl) {
                        short8 bb = *(const short8*)&wl[(ntl * 16 + m) * 136 + kc * 32 + hi * 8];
                        acc[hh * 4 + ntl] =
                            __builtin_amdgcn_mfma_f32_16x16x32_bf16(a, bb, acc[hh * 4 + ntl], 0, 0, 0);
                    }
                }
                __syncthreads();
            }

            // Y2 -> xl (bf16) + BN partials
#pragma unroll
            for (int nt = 0; nt < 8; ++nt) {
                float bv = p.b2[nt * 16 + m];
                float ss = 0.f, qq = 0.f;
#pragma unroll
                for (int r = 0; r < 4; ++r) {
                    int row = wv * 16 + hi * 4 + r;
                    float v = acc[nt][r] + bv;
                    xl[row * 136 + nt * 16 + m] = f2bf(v);
                    if (b * TSZ + row < NN) { ss += v; qq += v * v; }
                }
                sred[(nt * 16 + m) * 16 + wv * 4 + hi] = ss;
                qred[(nt * 16 + m) * 16 + wv * 4 + hi] = qq;
            }
            __syncthreads();

            // coalesced Y2 store + stats reduce
#pragma unroll
            for (int l = 0; l < 4; ++l) {
                int idx = t + l * 256;
                int row = idx >> 4, c = idx & 15;
                int g = b * TSZ + row;
                if (g < NN)
                    ((short8*)p.xb)[g * 16 + c] = *(const short8*)&xl[row * 136 + c * 8];
            }
            if (t < 128) {
                float s = 0.f, q = 0.f;
#pragma unroll
                for (int j = 0; j < 16; ++j) { s += sred[t * 16 + j]; q += qred[t * 16 + j]; }
                atomicAdd(&p.stats[t], s);
                atomicAdd(&p.stats[DD + t], q);
            }
        }
    }
    grid.sync();

    // ---- PC: out = h + relu(Y2*scale + shift) ----
    {
        const float invN = 1.0f / (float)NN;
        int t0 = bid * 256 + t;
        int cc = t0 & 15;
        float sc[8], sh[8];
#pragma unroll
        for (int j = 0; j < 8; ++j) {
            int col = cc * 8 + j;
            float mu = p.stats[col] * invN;
            float var = p.stats[DD + col] * invN - mu * mu;
            float s = rsqrtf(var + BN_EPS) * p.gamma[col];
            sc[j] = s;
            sh[j] = p.beta[col] - mu * s;
        }
        const short8* Y8 = (const short8*)p.xb;
        const float4* H4 = (const float4*)p.h;
        float4* O4 = (float4*)p.out;
        const int total = NN * 16;
        const int stride = nb * 256;   // multiple of 16 -> column octet fixed
        for (int i = t0; i < total; i += stride) {
            short8 u = Y8[i];
            float4 h0 = H4[2 * i], h1 = H4[2 * i + 1];
            float4 r0, r1;
            r0.x = h0.x + fmaxf(bf2f((unsigned short)u[0]) * sc[0] + sh[0], 0.f);
            r0.y = h0.y + fmaxf(bf2f((unsigned short)u[1]) * sc[1] + sh[1], 0.f);
            r0.z = h0.z + fmaxf(bf2f((unsigned short)u[2]) * sc[2] + sh[2], 0.f);
            r0.w = h0.w + fmaxf(bf2f((unsigned short)u[3]) * sc[3] + sh[3], 0.f);
            r1.x = h1.x + fmaxf(bf2f((unsigned short)u[4]) * sc[4] + sh[4], 0.f);
            r1.y = h1.y + fmaxf(bf2f((unsigned short)u[5]) * sc[5] + sh[5], 0.f);
            r1.z = h1.z + fmaxf(bf2f((unsigned short)u[6]) * sc[6] + sh[6], 0.f);
            r1.w = h1.w + fmaxf(bf2f((unsigned short)u[7]) * sc[7] + sh[7], 0.f);
            O4[2 * i] = r0;
            O4[2 * i + 1] = r1;
        }
    }
}

// ---------------------------------------------------------------------------
extern "C" void kernel_launch(void* const* d_in, const int* in_sizes, int n_in,
                              void* d_out, int out_size, void* d_ws, size_t ws_size,
                              hipStream_t stream)
{
    GinParams prm;
    prm.h     = (const float*)d_in[0];
    prm.src   = (const int*)d_in[1];
    prm.dst   = (const int*)d_in[2];
    prm.eps   = (const float*)d_in[3];
    prm.W1    = (const float*)d_in[4];
    prm.b1    = (const float*)d_in[5];
    prm.W2    = (const float*)d_in[6];
    prm.b2    = (const float*)d_in[7];
    prm.gamma = (const float*)d_in[8];
    prm.beta  = (const float*)d_in[9];
    prm.out   = (float*)d_out;

    char* w = (char*)d_ws;
    size_t o = 0;
    prm.stats  = (float*)(w + o); o += 256 * 4;
    prm.scnt   = (int*)(w + o); o += 512 * 4;
    prm.ticket = (int*)(w + o); o += 16;
    prm.W1t    = (unsigned short*)(w + o); o += (size_t)DD * DD * 2;
    prm.W2t    = (unsigned short*)(w + o); o += (size_t)DD * DD * 2;
    prm.off2   = (int2*)(w + o); o += (size_t)NSB * SBSZ * 8;    // 800 KB
    prm.sbuf   = (int*)(w + o); o += (size_t)NSB * CAPS * 4;     // 7.2 MB
    prm.xb     = (unsigned short*)(w + o); o += (size_t)NN * DD * 2;
    prm.hb     = (unsigned short*)(w + o); o += (size_t)NN * DD * 2;
    const int use_hb = (ws_size >= o) ? 1 : 0;

    int maxb = 0;
    if (use_hb)
        hipOccupancyMaxActiveBlocksPerMultiprocessor(&maxb, gin_mega2_kernel<true>, 256, 0);
    else
        hipOccupancyMaxActiveBlocksPerMultiprocessor(&maxb, gin_mega2_kernel<false>, 256, 0);
    if (maxb <= 0) maxb = 4;
    int grid = maxb * 256;
    if (grid > GRIDSZ) grid = GRIDSZ;
    if (grid < 512) grid = 512;   // need >= NSB(391) active blocks in PA2

    void* kargs[] = { &prm };
    if (use_hb)
        hipLaunchCooperativeKernel(reinterpret_cast<void*>(gin_mega2_kernel<true>),
                                   dim3(grid), dim3(256), kargs, 0, stream);
    else
        hipLaunchCooperativeKernel(reinterpret_cast<void*>(gin_mega2_kernel<false>),
                                   dim3(grid), dim3(256), kargs, 0, stream);
}

// Round 9
// 304.233 us; speedup vs baseline: 1.9816x; 1.9816x over previous
//
#include <hip/hip_runtime.h>

#define NN 100000
#define NE 1600000
#define DD 128
#define BN_EPS 1e-5f

#define SBSH 9                         // log2(super-bucket size)
#define SBSZ 512                       // nodes per super-bucket
#define NSB ((NN + SBSZ - 1) / SBSZ)   // 196 super-buckets
#define CAPS 9216                      // slots per bucket (mean 8163 + ~11 sigma)
#define EPB 8192                       // edges per pass-1 block
#define NBLK ((NE + EPB - 1) / EPB)    // 196 scatter blocks
#define PREPBLKS 828
#define GRID_PS (NBLK + PREPBLKS)      // 1024
#define BN_BLOCKS 1024

typedef __attribute__((ext_vector_type(8))) short short8;
typedef __attribute__((ext_vector_type(4))) float floatx4;

__device__ __forceinline__ unsigned short f2bf(float f) {
    union { float f; unsigned u; } v; v.f = f;
    return (unsigned short)((v.u + 0x7FFFu + ((v.u >> 16) & 1u)) >> 16);
}
__device__ __forceinline__ float bf2f(unsigned short u) {
    union { unsigned u; float f; } v; v.u = ((unsigned)u) << 16;
    return v.f;
}

// ---------------------------------------------------------------------------
// K1 (fused): blocks [0,196) = super-bucket radix scatter (chunk-reserved
// direct scatter, ~42-edge single-writer chunks); blocks [196,1024) = prep
// (W->bf16 transpose + h->bf16 copy). scnt zeroed by preceding memset.
// ---------------------------------------------------------------------------
__global__ __launch_bounds__(256) void prep_scatter_kernel(
    const float* __restrict__ W1, const float* __restrict__ W2,
    unsigned short* __restrict__ W1t, unsigned short* __restrict__ W2t,
    const float* __restrict__ h, unsigned short* __restrict__ hb, int do_hb,
    const int* __restrict__ src, const int* __restrict__ dst,
    int* __restrict__ scnt, int* __restrict__ sbuf)
{
    __shared__ int bins[256];
    int t = threadIdx.x;

    if (blockIdx.x < NBLK) {
        bins[t] = 0;
        __syncthreads();
        int base = blockIdx.x * EPB;
        int ecnt = min(EPB, NE - base);
        for (int i = t; i < ecnt; i += 256)
            atomicAdd(&bins[dst[base + i] >> SBSH], 1);
        __syncthreads();
        int c = bins[t];
        int gb = (t < NSB && c) ? atomicAdd(&scnt[t], c) : 0;
        __syncthreads();
        bins[t] = t * CAPS + gb;   // global chunk cursor for this block
        __syncthreads();
        for (int i = t; i < ecnt; i += 256) {
            int d = dst[base + i];
            int p = atomicAdd(&bins[d >> SBSH], 1);
            sbuf[p] = (src[base + i] << SBSH) | (d & (SBSZ - 1));
        }
    } else {
        int tid0 = (blockIdx.x - NBLK) * 256 + t;
        int stride = PREPBLKS * 256;
        for (int i = tid0; i < DD * DD; i += stride) {
            int n = i >> 7, k = i & 127;
            W1t[i] = f2bf(W1[k * DD + n]);
            W2t[i] = f2bf(W2[k * DD + n]);
        }
        if (do_hb) {
            const float4* h4 = (const float4*)h;
            ushort4* hb4 = (ushort4*)hb;
            for (int i = tid0; i < NN * (DD / 4); i += stride) {
                float4 v = h4[i];
                ushort4 o;
                o.x = f2bf(v.x); o.y = f2bf(v.y); o.z = f2bf(v.z); o.w = f2bf(v.w);
                hb4[i] = o;
            }
        }
    }
}

// ---------------------------------------------------------------------------
// K2: per-super-bucket CSR permute. One 512-thread block per bucket: LDS
// stage, per-node count+scan, off2[node]={beg,end} absolute, in-place
// permute of src indices (single-writer 36KB region).
// ---------------------------------------------------------------------------
__global__ __launch_bounds__(512) void permute_kernel(
    const int* __restrict__ scnt, int* __restrict__ sbuf,
    int2* __restrict__ off2)
{
    __shared__ int ew[CAPS];          // 36864 B
    __shared__ int cnt[SBSZ];
    __shared__ int cur[SBSZ];
    __shared__ int stmp[512];
    int sb = blockIdx.x, t = threadIdx.x;
    cnt[t] = 0;
    __syncthreads();
    int n = min(scnt[sb], CAPS);
    int sbase = sb * CAPS;
    for (int i = t; i < n; i += 512) {
        int e = sbuf[sbase + i];
        ew[i] = e;
        atomicAdd(&cnt[e & (SBSZ - 1)], 1);
    }
    __syncthreads();
    int c = cnt[t];
    stmp[t] = c;
    __syncthreads();
#pragma unroll
    for (int ofs = 1; ofs < 512; ofs <<= 1) {
        int u = (t >= ofs) ? stmp[t - ofs] : 0;
        __syncthreads();
        stmp[t] += u;
        __syncthreads();
    }
    int excl = stmp[t] - c;
    cur[t] = excl;
    off2[sb * SBSZ + t] = make_int2(sbase + excl, sbase + excl + c);
    __syncthreads();
    for (int i = t; i < n; i += 512) {
        int e = ew[i];
        int p = atomicAdd(&cur[e & (SBSZ - 1)], 1);
        sbuf[sbase + p] = e >> SBSH;   // in place (staged in LDS)
    }
}

// ---------------------------------------------------------------------------
// K3a: standalone gather (the proven 64us config: 16 lanes/node, unroll-4,
// 16 nodes/block, no LDS, high occupancy). xb = bf16((1+eps)*h + sum).
// ---------------------------------------------------------------------------
__global__ __launch_bounds__(256) void gather_bf16_kernel(
    const float* __restrict__ h, const unsigned short* __restrict__ hb,
    const float* __restrict__ eps, const int2* __restrict__ off2,
    const int* __restrict__ srcs, unsigned short* __restrict__ xb)
{
    int node = blockIdx.x * 16 + (threadIdx.x >> 4);
    if (node >= NN) return;
    int c8 = threadIdx.x & 15;
    const float s = 1.0f + eps[0];
    const float4* h4 = (const float4*)h;
    float4 a0 = h4[node * 32 + c8 * 2];
    float4 a1 = h4[node * 32 + c8 * 2 + 1];
    float acc[8] = {s * a0.x, s * a0.y, s * a0.z, s * a0.w,
                    s * a1.x, s * a1.y, s * a1.z, s * a1.w};
    int2 oo = off2[node];
    int e = oo.x, eend = oo.y;
    const short8* hb8 = (const short8*)hb;
    for (; e + 3 < eend; e += 4) {
        int s0 = srcs[e],     s1 = srcs[e + 1];
        int s2 = srcs[e + 2], s3 = srcs[e + 3];
        short8 v0 = hb8[s0 * 16 + c8];
        short8 v1 = hb8[s1 * 16 + c8];
        short8 v2 = hb8[s2 * 16 + c8];
        short8 v3 = hb8[s3 * 16 + c8];
#pragma unroll
        for (int j = 0; j < 8; ++j) {
            float t0 = bf2f((unsigned short)v0[j]) + bf2f((unsigned short)v1[j]);
            float t1 = bf2f((unsigned short)v2[j]) + bf2f((unsigned short)v3[j]);
            acc[j] += t0 + t1;
        }
    }
    for (; e < eend; ++e) {
        short8 v0 = hb8[srcs[e] * 16 + c8];
#pragma unroll
        for (int j = 0; j < 8; ++j) acc[j] += bf2f((unsigned short)v0[j]);
    }
    short8 o;
#pragma unroll
    for (int j = 0; j < 8; ++j) o[j] = (short)f2bf(acc[j]);
    ((short8*)xb)[node * 16 + c8] = o;
}

// f32 fallback (no hb copy)
__global__ __launch_bounds__(256) void gather_f32_kernel(
    const float* __restrict__ h, const float* __restrict__ eps,
    const int2* __restrict__ off2, const int* __restrict__ srcs,
    unsigned short* __restrict__ xb)
{
    int node = blockIdx.x * 16 + (threadIdx.x >> 4);
    if (node >= NN) return;
    int c8 = threadIdx.x & 15;
    const float4* h4 = (const float4*)h;
    const float s = 1.0f + eps[0];
    float4 a0 = h4[node * 32 + c8 * 2];
    float4 a1 = h4[node * 32 + c8 * 2 + 1];
    float acc[8] = {s * a0.x, s * a0.y, s * a0.z, s * a0.w,
                    s * a1.x, s * a1.y, s * a1.z, s * a1.w};
    int2 oo = off2[node];
    int e = oo.x, eend = oo.y;
    for (; e + 1 < eend; e += 2) {
        int s0 = srcs[e], s1 = srcs[e + 1];
        float4 u0 = h4[s0 * 32 + c8 * 2], u1 = h4[s0 * 32 + c8 * 2 + 1];
        float4 w0 = h4[s1 * 32 + c8 * 2], w1 = h4[s1 * 32 + c8 * 2 + 1];
        acc[0] += u0.x + w0.x; acc[1] += u0.y + w0.y;
        acc[2] += u0.z + w0.z; acc[3] += u0.w + w0.w;
        acc[4] += u1.x + w1.x; acc[5] += u1.y + w1.y;
        acc[6] += u1.z + w1.z; acc[7] += u1.w + w1.w;
    }
    if (e < eend) {
        int s0 = srcs[e];
        float4 u0 = h4[s0 * 32 + c8 * 2], u1 = h4[s0 * 32 + c8 * 2 + 1];
        acc[0] += u0.x; acc[1] += u0.y; acc[2] += u0.z; acc[3] += u0.w;
        acc[4] += u1.x; acc[5] += u1.y; acc[6] += u1.z; acc[7] += u1.w;
    }
    short8 o;
#pragma unroll
    for (int j = 0; j < 8; ++j) o[j] = (short)f2bf(acc[j]);
    ((short8*)xb)[node * 16 + c8] = o;
}

// ---------------------------------------------------------------------------
// K3b: fused 2-layer MLP + BN stats (R2-proven body). Y1 stays in LDS; W
// full-staged per GEMM; stats epilogue masked to valid rows. In-place safe.
// ---------------------------------------------------------------------------
__global__ __launch_bounds__(256) void mlp_fused_kernel(
    const unsigned short* __restrict__ X,
    const unsigned short* __restrict__ W1t, const unsigned short* __restrict__ W2t,
    const float* __restrict__ b1, const float* __restrict__ b2,
    unsigned short* __restrict__ Y, float* __restrict__ stats)
{
    extern __shared__ char smem[];
    unsigned short* wl = (unsigned short*)smem;            // [128][136] bf16
    unsigned short* xl = (unsigned short*)(smem + 34816);  // [64][136] bf16

    const int tid = threadIdx.x;
    const int r0 = blockIdx.x * 64;
    const int lane = tid & 63;
    const int wv = tid >> 6;
    const int m = lane & 15;
    const int hi = lane >> 4;

    const short8* W18 = (const short8*)W1t;
#pragma unroll
    for (int l = 0; l < 8; ++l) {
        int idx = tid + l * 256;
        int n = idx >> 4, c = idx & 15;
        *(short8*)&wl[n * 136 + c * 8] = W18[idx];
    }
    const short8* X8 = (const short8*)X;
#pragma unroll
    for (int l = 0; l < 4; ++l) {
        int idx = tid + l * 256;
        int row = idx >> 4, c = idx & 15;
        int g = r0 + row;
        short8 v = {0, 0, 0, 0, 0, 0, 0, 0};
        if (g < NN) v = X8[g * 16 + c];
        *(short8*)&xl[row * 136 + c * 8] = v;
    }
    __syncthreads();

    floatx4 acc[8];
#pragma unroll
    for (int i = 0; i < 8; ++i) acc[i] = (floatx4){0.f, 0.f, 0.f, 0.f};
#pragma unroll
    for (int kc = 0; kc < 4; ++kc) {
        short8 a = *(const short8*)&xl[(wv * 16 + m) * 136 + kc * 32 + hi * 8];
#pragma unroll
        for (int nt = 0; nt < 8; ++nt) {
            short8 b = *(const short8*)&wl[(nt * 16 + m) * 136 + kc * 32 + hi * 8];
            acc[nt] = __builtin_amdgcn_mfma_f32_16x16x32_bf16(a, b, acc[nt], 0, 0, 0);
        }
    }
    __syncthreads();

#pragma unroll
    for (int nt = 0; nt < 8; ++nt) {
        float bv = b1[nt * 16 + m];
#pragma unroll
        for (int r = 0; r < 4; ++r) {
            float v = fmaxf(acc[nt][r] + bv, 0.f);
            xl[(wv * 16 + hi * 4 + r) * 136 + nt * 16 + m] = f2bf(v);
        }
    }
    const short8* W28 = (const short8*)W2t;
#pragma unroll
    for (int l = 0; l < 8; ++l) {
        int idx = tid + l * 256;
        int n = idx >> 4, c = idx & 15;
        *(short8*)&wl[n * 136 + c * 8] = W28[idx];
    }
    __syncthreads();

#pragma unroll
    for (int i = 0; i < 8; ++i) acc[i] = (floatx4){0.f, 0.f, 0.f, 0.f};
#pragma unroll
    for (int kc = 0; kc < 4; ++kc) {
        short8 a = *(const short8*)&xl[(wv * 16 + m) * 136 + kc * 32 + hi * 8];
#pragma unroll
        for (int nt = 0; nt < 8; ++nt) {
            short8 b = *(const short8*)&wl[(nt * 16 + m) * 136 + kc * 32 + hi * 8];
            acc[nt] = __builtin_amdgcn_mfma_f32_16x16x32_bf16(a, b, acc[nt], 0, 0, 0);
        }
    }
    __syncthreads();

#pragma unroll
    for (int nt = 0; nt < 8; ++nt) {
        float bv = b2[nt * 16 + m];
#pragma unroll
        for (int r = 0; r < 4; ++r) {
            float v = acc[nt][r] + bv;
            xl[(wv * 16 + hi * 4 + r) * 136 + nt * 16 + m] = f2bf(v);
        }
    }
    __syncthreads();

#pragma unroll
    for (int l = 0; l < 4; ++l) {
        int idx = tid + l * 256;
        int row = idx >> 4, c = idx & 15;
        int g = r0 + row;
        if (g < NN)
            ((short8*)Y)[g * 16 + c] = *(const short8*)&xl[row * 136 + c * 8];
    }

    int col = tid & 127, half = tid >> 7;
    int rlim = min(64, NN - r0);
    int rbeg = half * 32, rend = min(rbeg + 32, rlim);
    float s = 0.f, q = 0.f;
    for (int r = rbeg; r < rend; ++r) {
        float v = bf2f(xl[r * 136 + col]);
        s += v; q += v * v;
    }
    float* red = (float*)wl;
    red[tid] = s;
    red[256 + tid] = q;
    __syncthreads();
    if (half == 0) {
        atomicAdd(&stats[col],      red[col] + red[128 + col]);
        atomicAdd(&stats[DD + col], red[256 + col] + red[256 + 128 + col]);
    }
}

// ---------------------------------------------------------------------------
// K4: out = h + relu(Y*scale + shift). BN math hoisted (column octet fixed).
// ---------------------------------------------------------------------------
__global__ __launch_bounds__(256) void bn_final_kernel(
    const unsigned short* __restrict__ Y, const float* __restrict__ h,
    const float* __restrict__ gamma, const float* __restrict__ beta,
    const float* __restrict__ stats, float* __restrict__ out)
{
    const float invN = 1.0f / (float)NN;
    int t0 = blockIdx.x * 256 + threadIdx.x;
    int c8 = t0 & 15;
    float sc[8], sh[8];
#pragma unroll
    for (int j = 0; j < 8; ++j) {
        int col = c8 * 8 + j;
        float mu = stats[col] * invN;
        float var = stats[DD + col] * invN - mu * mu;
        float s = rsqrtf(var + BN_EPS) * gamma[col];
        sc[j] = s;
        sh[j] = beta[col] - mu * s;
    }
    const short8* Y8 = (const short8*)Y;
    const float4* H4 = (const float4*)h;
    float4* O4 = (float4*)out;
    const int total = NN * 16;
    const int stride = BN_BLOCKS * 256;
    for (int i = t0; i < total; i += stride) {
        short8 u = Y8[i];
        float4 h0 = H4[2 * i], h1 = H4[2 * i + 1];
        float4 r0, r1;
        r0.x = h0.x + fmaxf(bf2f((unsigned short)u[0]) * sc[0] + sh[0], 0.f);
        r0.y = h0.y + fmaxf(bf2f((unsigned short)u[1]) * sc[1] + sh[1], 0.f);
        r0.z = h0.z + fmaxf(bf2f((unsigned short)u[2]) * sc[2] + sh[2], 0.f);
        r0.w = h0.w + fmaxf(bf2f((unsigned short)u[3]) * sc[3] + sh[3], 0.f);
        r1.x = h1.x + fmaxf(bf2f((unsigned short)u[4]) * sc[4] + sh[4], 0.f);
        r1.y = h1.y + fmaxf(bf2f((unsigned short)u[5]) * sc[5] + sh[5], 0.f);
        r1.z = h1.z + fmaxf(bf2f((unsigned short)u[6]) * sc[6] + sh[6], 0.f);
        r1.w = h1.w + fmaxf(bf2f((unsigned short)u[7]) * sc[7] + sh[7], 0.f);
        O4[2 * i] = r0;
        O4[2 * i + 1] = r1;
    }
}

// ---------------------------------------------------------------------------
extern "C" void kernel_launch(void* const* d_in, const int* in_sizes, int n_in,
                              void* d_out, int out_size, void* d_ws, size_t ws_size,
                              hipStream_t stream)
{
    const float* h     = (const float*)d_in[0];
    const int*   src   = (const int*)d_in[1];
    const int*   dst   = (const int*)d_in[2];
    const float* eps   = (const float*)d_in[3];
    const float* W1    = (const float*)d_in[4];
    const float* b1    = (const float*)d_in[5];
    const float* W2    = (const float*)d_in[6];
    const float* b2    = (const float*)d_in[7];
    const float* gamma = (const float*)d_in[8];
    const float* beta  = (const float*)d_in[9];
    float* out = (float*)d_out;

    char* w = (char*)d_ws;
    size_t o = 0;
    float* stats    = (float*)(w + o); o += 256 * 4;                 // memset
    int* scnt       = (int*)(w + o); o += 256 * 4;                   // memset
    unsigned short* W1t = (unsigned short*)(w + o); o += (size_t)DD * DD * 2;
    unsigned short* W2t = (unsigned short*)(w + o); o += (size_t)DD * DD * 2;
    int2* off2      = (int2*)(w + o); o += (size_t)NSB * SBSZ * 8;   // 802816
    int* sbuf       = (int*)(w + o); o += (size_t)NSB * CAPS * 4;    // 7.2 MB
    unsigned short* xb  = (unsigned short*)(w + o); o += (size_t)NN * DD * 2;
    unsigned short* hb  = (unsigned short*)(w + o); o += (size_t)NN * DD * 2;
    const int use_hb = (ws_size >= o) ? 1 : 0;  // launch-constant

    // 0. zero stats + super-bucket cursors (contiguous 2 KB)
    hipMemsetAsync(stats, 0, 512 * sizeof(int), stream);

    // 1. fused prep + radix scatter
    prep_scatter_kernel<<<GRID_PS, 256, 0, stream>>>(
        W1, W2, W1t, W2t, h, hb, use_hb, src, dst, scnt, sbuf);

    // 2. per-super-bucket CSR permute
    permute_kernel<<<NSB, 512, 0, stream>>>(scnt, sbuf, off2);

    // 3. standalone gather (high-occupancy, proven 64us config)
    if (use_hb)
        gather_bf16_kernel<<<(NN + 15) / 16, 256, 0, stream>>>(h, hb, eps, off2, sbuf, xb);
    else
        gather_f32_kernel<<<(NN + 15) / 16, 256, 0, stream>>>(h, eps, off2, sbuf, xb);

    // 4. fused 2-layer MLP + BN stats (in place on xb)
    size_t gemm_lds = 34816 + 17408;   // 52224 B
    mlp_fused_kernel<<<(NN + 63) / 64, 256, gemm_lds, stream>>>(
        xb, W1t, W2t, b1, b2, xb, stats);

    // 5. out = h + relu(BN(y2))
    bn_final_kernel<<<BN_BLOCKS, 256, 0, stream>>>(xb, h, gamma, beta, stats, out);
}

// Round 10
// 289.110 us; speedup vs baseline: 2.0853x; 1.0523x over previous
//
#include <hip/hip_runtime.h>

#define NN 100000
#define NE 1600000
#define DD 128
#define BN_EPS 1e-5f

#define SBSH 9                         // log2(super-bucket size)
#define SBSZ 512                       // nodes per super-bucket
#define NSB ((NN + SBSZ - 1) / SBSZ)   // 196 super-buckets
#define CAPS 9216                      // slots per bucket (mean 8163 + ~11 sigma)
#define EPB 8192                       // edges per pass-1 block
#define NBLK ((NE + EPB - 1) / EPB)    // 196 scatter blocks
#define PREPBLKS 828
#define GRID_PS (NBLK + PREPBLKS)      // 1024
#define BN_BLOCKS 1024
#define HALF_NODES 50000               // gather split point (50000/16 = 3125 blocks)

typedef __attribute__((ext_vector_type(8))) short short8;
typedef __attribute__((ext_vector_type(4))) float floatx4;

__device__ __forceinline__ unsigned short f2bf(float f) {
    union { float f; unsigned u; } v; v.f = f;
    return (unsigned short)((v.u + 0x7FFFu + ((v.u >> 16) & 1u)) >> 16);
}
__device__ __forceinline__ float bf2f(unsigned short u) {
    union { unsigned u; float f; } v; v.u = ((unsigned)u) << 16;
    return v.f;
}

// ---------------------------------------------------------------------------
// K1 (fused): blocks [0,196) = super-bucket radix scatter (chunk-reserved
// direct scatter); blocks [196,1024) = prep (W->bf16 transpose + h->bf16).
// scnt zeroed by preceding memset.
// ---------------------------------------------------------------------------
__global__ __launch_bounds__(256) void prep_scatter_kernel(
    const float* __restrict__ W1, const float* __restrict__ W2,
    unsigned short* __restrict__ W1t, unsigned short* __restrict__ W2t,
    const float* __restrict__ h, unsigned short* __restrict__ hb, int do_hb,
    const int* __restrict__ src, const int* __restrict__ dst,
    int* __restrict__ scnt, int* __restrict__ sbuf)
{
    __shared__ int bins[256];
    int t = threadIdx.x;

    if (blockIdx.x < NBLK) {
        bins[t] = 0;
        __syncthreads();
        int base = blockIdx.x * EPB;
        int ecnt = min(EPB, NE - base);
        for (int i = t; i < ecnt; i += 256)
            atomicAdd(&bins[dst[base + i] >> SBSH], 1);
        __syncthreads();
        int c = bins[t];
        int gb = (t < NSB && c) ? atomicAdd(&scnt[t], c) : 0;
        __syncthreads();
        bins[t] = t * CAPS + gb;   // global chunk cursor for this block
        __syncthreads();
        for (int i = t; i < ecnt; i += 256) {
            int d = dst[base + i];
            int p = atomicAdd(&bins[d >> SBSH], 1);
            sbuf[p] = (src[base + i] << SBSH) | (d & (SBSZ - 1));
        }
    } else {
        int tid0 = (blockIdx.x - NBLK) * 256 + t;
        int stride = PREPBLKS * 256;
        for (int i = tid0; i < DD * DD; i += stride) {
            int n = i >> 7, k = i & 127;
            W1t[i] = f2bf(W1[k * DD + n]);
            W2t[i] = f2bf(W2[k * DD + n]);
        }
        if (do_hb) {
            const float4* h4 = (const float4*)h;
            ushort4* hb4 = (ushort4*)hb;
            for (int i = tid0; i < NN * (DD / 4); i += stride) {
                float4 v = h4[i];
                ushort4 o;
                o.x = f2bf(v.x); o.y = f2bf(v.y); o.z = f2bf(v.z); o.w = f2bf(v.w);
                hb4[i] = o;
            }
        }
    }
}

// ---------------------------------------------------------------------------
// K2: per-super-bucket CSR permute (LDS stage, count+scan, in-place permute).
// ---------------------------------------------------------------------------
__global__ __launch_bounds__(512) void permute_kernel(
    const int* __restrict__ scnt, int* __restrict__ sbuf,
    int2* __restrict__ off2)
{
    __shared__ int ew[CAPS];          // 36864 B
    __shared__ int cnt[SBSZ];
    __shared__ int cur[SBSZ];
    __shared__ int stmp[512];
    int sb = blockIdx.x, t = threadIdx.x;
    cnt[t] = 0;
    __syncthreads();
    int n = min(scnt[sb], CAPS);
    int sbase = sb * CAPS;
    for (int i = t; i < n; i += 512) {
        int e = sbuf[sbase + i];
        ew[i] = e;
        atomicAdd(&cnt[e & (SBSZ - 1)], 1);
    }
    __syncthreads();
    int c = cnt[t];
    stmp[t] = c;
    __syncthreads();
#pragma unroll
    for (int ofs = 1; ofs < 512; ofs <<= 1) {
        int u = (t >= ofs) ? stmp[t - ofs] : 0;
        __syncthreads();
        stmp[t] += u;
        __syncthreads();
    }
    int excl = stmp[t] - c;
    cur[t] = excl;
    off2[sb * SBSZ + t] = make_int2(sbase + excl, sbase + excl + c);
    __syncthreads();
    for (int i = t; i < n; i += 512) {
        int e = ew[i];
        int p = atomicAdd(&cur[e & (SBSZ - 1)], 1);
        sbuf[sbase + p] = e >> SBSH;   // in place (staged in LDS)
    }
}

// ---------------------------------------------------------------------------
// K3a/K3b: gather over a node RANGE [node0, node0+span) -- launched twice so
// each dispatch is ~33us and the top-5 finally surfaces K1/K2/mlp/bn with
// real counters (attribution round). Body identical to the proven 64us config.
// ---------------------------------------------------------------------------
__global__ __launch_bounds__(256) void gather_bf16_kernel(
    const float* __restrict__ h, const unsigned short* __restrict__ hb,
    const float* __restrict__ eps, const int2* __restrict__ off2,
    const int* __restrict__ srcs, unsigned short* __restrict__ xb, int node0)
{
    int node = node0 + blockIdx.x * 16 + (threadIdx.x >> 4);
    if (node >= NN) return;
    int c8 = threadIdx.x & 15;
    const float s = 1.0f + eps[0];
    const float4* h4 = (const float4*)h;
    float4 a0 = h4[node * 32 + c8 * 2];
    float4 a1 = h4[node * 32 + c8 * 2 + 1];
    float acc[8] = {s * a0.x, s * a0.y, s * a0.z, s * a0.w,
                    s * a1.x, s * a1.y, s * a1.z, s * a1.w};
    int2 oo = off2[node];
    int e = oo.x, eend = oo.y;
    const short8* hb8 = (const short8*)hb;
    for (; e + 3 < eend; e += 4) {
        int s0 = srcs[e],     s1 = srcs[e + 1];
        int s2 = srcs[e + 2], s3 = srcs[e + 3];
        short8 v0 = hb8[s0 * 16 + c8];
        short8 v1 = hb8[s1 * 16 + c8];
        short8 v2 = hb8[s2 * 16 + c8];
        short8 v3 = hb8[s3 * 16 + c8];
#pragma unroll
        for (int j = 0; j < 8; ++j) {
            float t0 = bf2f((unsigned short)v0[j]) + bf2f((unsigned short)v1[j]);
            float t1 = bf2f((unsigned short)v2[j]) + bf2f((unsigned short)v3[j]);
            acc[j] += t0 + t1;
        }
    }
    for (; e < eend; ++e) {
        short8 v0 = hb8[srcs[e] * 16 + c8];
#pragma unroll
        for (int j = 0; j < 8; ++j) acc[j] += bf2f((unsigned short)v0[j]);
    }
    short8 o;
#pragma unroll
    for (int j = 0; j < 8; ++j) o[j] = (short)f2bf(acc[j]);
    ((short8*)xb)[node * 16 + c8] = o;
}

__global__ __launch_bounds__(256) void gather_f32_kernel(
    const float* __restrict__ h, const float* __restrict__ eps,
    const int2* __restrict__ off2, const int* __restrict__ srcs,
    unsigned short* __restrict__ xb, int node0)
{
    int node = node0 + blockIdx.x * 16 + (threadIdx.x >> 4);
    if (node >= NN) return;
    int c8 = threadIdx.x & 15;
    const float4* h4 = (const float4*)h;
    const float s = 1.0f + eps[0];
    float4 a0 = h4[node * 32 + c8 * 2];
    float4 a1 = h4[node * 32 + c8 * 2 + 1];
    float acc[8] = {s * a0.x, s * a0.y, s * a0.z, s * a0.w,
                    s * a1.x, s * a1.y, s * a1.z, s * a1.w};
    int2 oo = off2[node];
    int e = oo.x, eend = oo.y;
    for (; e + 1 < eend; e += 2) {
        int s0 = srcs[e], s1 = srcs[e + 1];
        float4 u0 = h4[s0 * 32 + c8 * 2], u1 = h4[s0 * 32 + c8 * 2 + 1];
        float4 w0 = h4[s1 * 32 + c8 * 2], w1 = h4[s1 * 32 + c8 * 2 + 1];
        acc[0] += u0.x + w0.x; acc[1] += u0.y + w0.y;
        acc[2] += u0.z + w0.z; acc[3] += u0.w + w0.w;
        acc[4] += u1.x + w1.x; acc[5] += u1.y + w1.y;
        acc[6] += u1.z + w1.z; acc[7] += u1.w + w1.w;
    }
    if (e < eend) {
        int s0 = srcs[e];
        float4 u0 = h4[s0 * 32 + c8 * 2], u1 = h4[s0 * 32 + c8 * 2 + 1];
        acc[0] += u0.x; acc[1] += u0.y; acc[2] += u0.z; acc[3] += u0.w;
        acc[4] += u1.x; acc[5] += u1.y; acc[6] += u1.z; acc[7] += u1.w;
    }
    short8 o;
#pragma unroll
    for (int j = 0; j < 8; ++j) o[j] = (short)f2bf(acc[j]);
    ((short8*)xb)[node * 16 + c8] = o;
}

// ---------------------------------------------------------------------------
// K4: fused 2-layer MLP + BN stats, 128-row / 512-thread tile. W staged once
// per layer per 128 rows (half the staging traffic/barriers of the 64-row
// version). LDS: wl 34816 + xl 34816 = 69632 -> 2 blocks/CU, 16 waves/CU.
// ---------------------------------------------------------------------------
__global__ __launch_bounds__(512) void mlp_fused_kernel(
    const unsigned short* __restrict__ X,
    const unsigned short* __restrict__ W1t, const unsigned short* __restrict__ W2t,
    const float* __restrict__ b1, const float* __restrict__ b2,
    unsigned short* __restrict__ Y, float* __restrict__ stats)
{
    extern __shared__ char smem[];
    unsigned short* wl = (unsigned short*)smem;            // [128][136] bf16
    unsigned short* xl = (unsigned short*)(smem + 34816);  // [128][136] bf16

    const int tid = threadIdx.x;
    const int r0 = blockIdx.x * 128;
    const int lane = tid & 63;
    const int wv = tid >> 6;        // 0..7: wave's 16-row band
    const int m = lane & 15;
    const int hi = lane >> 4;

    const short8* W18 = (const short8*)W1t;
#pragma unroll
    for (int l = 0; l < 4; ++l) {
        int idx = tid + l * 512;
        int n = idx >> 4, c = idx & 15;
        *(short8*)&wl[n * 136 + c * 8] = W18[idx];
    }
    const short8* X8 = (const short8*)X;
#pragma unroll
    for (int l = 0; l < 4; ++l) {
        int idx = tid + l * 512;
        int row = idx >> 4, c = idx & 15;
        int g = r0 + row;
        short8 v = {0, 0, 0, 0, 0, 0, 0, 0};
        if (g < NN) v = X8[g * 16 + c];
        *(short8*)&xl[row * 136 + c * 8] = v;
    }
    __syncthreads();

    floatx4 acc[8];
#pragma unroll
    for (int i = 0; i < 8; ++i) acc[i] = (floatx4){0.f, 0.f, 0.f, 0.f};
#pragma unroll
    for (int kc = 0; kc < 4; ++kc) {
        short8 a = *(const short8*)&xl[(wv * 16 + m) * 136 + kc * 32 + hi * 8];
#pragma unroll
        for (int nt = 0; nt < 8; ++nt) {
            short8 b = *(const short8*)&wl[(nt * 16 + m) * 136 + kc * 32 + hi * 8];
            acc[nt] = __builtin_amdgcn_mfma_f32_16x16x32_bf16(a, b, acc[nt], 0, 0, 0);
        }
    }
    __syncthreads();

#pragma unroll
    for (int nt = 0; nt < 8; ++nt) {
        float bv = b1[nt * 16 + m];
#pragma unroll
        for (int r = 0; r < 4; ++r) {
            float v = fmaxf(acc[nt][r] + bv, 0.f);
            xl[(wv * 16 + hi * 4 + r) * 136 + nt * 16 + m] = f2bf(v);
        }
    }
    const short8* W28 = (const short8*)W2t;
#pragma unroll
    for (int l = 0; l < 4; ++l) {
        int idx = tid + l * 512;
        int n = idx >> 4, c = idx & 15;
        *(short8*)&wl[n * 136 + c * 8] = W28[idx];
    }
    __syncthreads();

#pragma unroll
    for (int i = 0; i < 8; ++i) acc[i] = (floatx4){0.f, 0.f, 0.f, 0.f};
#pragma unroll
    for (int kc = 0; kc < 4; ++kc) {
        short8 a = *(const short8*)&xl[(wv * 16 + m) * 136 + kc * 32 + hi * 8];
#pragma unroll
        for (int nt = 0; nt < 8; ++nt) {
            short8 b = *(const short8*)&wl[(nt * 16 + m) * 136 + kc * 32 + hi * 8];
            acc[nt] = __builtin_amdgcn_mfma_f32_16x16x32_bf16(a, b, acc[nt], 0, 0, 0);
        }
    }
    __syncthreads();

#pragma unroll
    for (int nt = 0; nt < 8; ++nt) {
        float bv = b2[nt * 16 + m];
#pragma unroll
        for (int r = 0; r < 4; ++r) {
            float v = acc[nt][r] + bv;
            xl[(wv * 16 + hi * 4 + r) * 136 + nt * 16 + m] = f2bf(v);
        }
    }
    __syncthreads();

    // coalesced Y2 store
#pragma unroll
    for (int l = 0; l < 4; ++l) {
        int idx = tid + l * 512;
        int row = idx >> 4, c = idx & 15;
        int g = r0 + row;
        if (g < NN)
            ((short8*)Y)[g * 16 + c] = *(const short8*)&xl[row * 136 + c * 8];
    }

    // BN partials: col = tid&127, quarter = tid>>7 covers 32 rows each
    int col = tid & 127, quarter = tid >> 7;
    int rlim = min(128, NN - r0);
    int rbeg = quarter * 32, rend = min(rbeg + 32, rlim);
    float s = 0.f, q = 0.f;
    for (int r = rbeg; r < rend; ++r) {
        float v = bf2f(xl[r * 136 + col]);
        s += v; q += v * v;
    }
    float* red = (float*)wl;        // wl dead after GEMM2
    red[tid] = s;
    red[512 + tid] = q;
    __syncthreads();
    if (tid < 128) {
        float ts = red[tid] + red[128 + tid] + red[256 + tid] + red[384 + tid];
        float tq = red[512 + tid] + red[640 + tid] + red[768 + tid] + red[896 + tid];
        atomicAdd(&stats[tid], ts);
        atomicAdd(&stats[DD + tid], tq);
    }
}

// ---------------------------------------------------------------------------
// K5: out = h + relu(Y*scale + shift). BN math hoisted (column octet fixed).
// ---------------------------------------------------------------------------
__global__ __launch_bounds__(256) void bn_final_kernel(
    const unsigned short* __restrict__ Y, const float* __restrict__ h,
    const float* __restrict__ gamma, const float* __restrict__ beta,
    const float* __restrict__ stats, float* __restrict__ out)
{
    const float invN = 1.0f / (float)NN;
    int t0 = blockIdx.x * 256 + threadIdx.x;
    int c8 = t0 & 15;
    float sc[8], sh[8];
#pragma unroll
    for (int j = 0; j < 8; ++j) {
        int col = c8 * 8 + j;
        float mu = stats[col] * invN;
        float var = stats[DD + col] * invN - mu * mu;
        float s = rsqrtf(var + BN_EPS) * gamma[col];
        sc[j] = s;
        sh[j] = beta[col] - mu * s;
    }
    const short8* Y8 = (const short8*)Y;
    const float4* H4 = (const float4*)h;
    float4* O4 = (float4*)out;
    const int total = NN * 16;
    const int stride = BN_BLOCKS * 256;
    for (int i = t0; i < total; i += stride) {
        short8 u = Y8[i];
        float4 h0 = H4[2 * i], h1 = H4[2 * i + 1];
        float4 r0, r1;
        r0.x = h0.x + fmaxf(bf2f((unsigned short)u[0]) * sc[0] + sh[0], 0.f);
        r0.y = h0.y + fmaxf(bf2f((unsigned short)u[1]) * sc[1] + sh[1], 0.f);
        r0.z = h0.z + fmaxf(bf2f((unsigned short)u[2]) * sc[2] + sh[2], 0.f);
        r0.w = h0.w + fmaxf(bf2f((unsigned short)u[3]) * sc[3] + sh[3], 0.f);
        r1.x = h1.x + fmaxf(bf2f((unsigned short)u[4]) * sc[4] + sh[4], 0.f);
        r1.y = h1.y + fmaxf(bf2f((unsigned short)u[5]) * sc[5] + sh[5], 0.f);
        r1.z = h1.z + fmaxf(bf2f((unsigned short)u[6]) * sc[6] + sh[6], 0.f);
        r1.w = h1.w + fmaxf(bf2f((unsigned short)u[7]) * sc[7] + sh[7], 0.f);
        O4[2 * i] = r0;
        O4[2 * i + 1] = r1;
    }
}

// ---------------------------------------------------------------------------
extern "C" void kernel_launch(void* const* d_in, const int* in_sizes, int n_in,
                              void* d_out, int out_size, void* d_ws, size_t ws_size,
                              hipStream_t stream)
{
    const float* h     = (const float*)d_in[0];
    const int*   src   = (const int*)d_in[1];
    const int*   dst   = (const int*)d_in[2];
    const float* eps   = (const float*)d_in[3];
    const float* W1    = (const float*)d_in[4];
    const float* b1    = (const float*)d_in[5];
    const float* W2    = (const float*)d_in[6];
    const float* b2    = (const float*)d_in[7];
    const float* gamma = (const float*)d_in[8];
    const float* beta  = (const float*)d_in[9];
    float* out = (float*)d_out;

    char* w = (char*)d_ws;
    size_t o = 0;
    float* stats    = (float*)(w + o); o += 256 * 4;                 // memset
    int* scnt       = (int*)(w + o); o += 256 * 4;                   // memset
    unsigned short* W1t = (unsigned short*)(w + o); o += (size_t)DD * DD * 2;
    unsigned short* W2t = (unsigned short*)(w + o); o += (size_t)DD * DD * 2;
    int2* off2      = (int2*)(w + o); o += (size_t)NSB * SBSZ * 8;   // 802816
    int* sbuf       = (int*)(w + o); o += (size_t)NSB * CAPS * 4;    // 7.2 MB
    unsigned short* xb  = (unsigned short*)(w + o); o += (size_t)NN * DD * 2;
    unsigned short* hb  = (unsigned short*)(w + o); o += (size_t)NN * DD * 2;
    const int use_hb = (ws_size >= o) ? 1 : 0;  // launch-constant

    // 0. zero stats + super-bucket cursors
    hipMemsetAsync(stats, 0, 512 * sizeof(int), stream);

    // 1. fused prep + radix scatter
    prep_scatter_kernel<<<GRID_PS, 256, 0, stream>>>(
        W1, W2, W1t, W2t, h, hb, use_hb, src, dst, scnt, sbuf);

    // 2. per-super-bucket CSR permute
    permute_kernel<<<NSB, 512, 0, stream>>>(scnt, sbuf, off2);

    // 3a/3b. gather in two half-node dispatches (attribution: each ~33us so
    // K1/K2/mlp/bn surface in top-5)
    if (use_hb) {
        gather_bf16_kernel<<<HALF_NODES / 16, 256, 0, stream>>>(h, hb, eps, off2, sbuf, xb, 0);
        gather_bf16_kernel<<<(NN - HALF_NODES + 15) / 16, 256, 0, stream>>>(h, hb, eps, off2, sbuf, xb, HALF_NODES);
    } else {
        gather_f32_kernel<<<HALF_NODES / 16, 256, 0, stream>>>(h, eps, off2, sbuf, xb, 0);
        gather_f32_kernel<<<(NN - HALF_NODES + 15) / 16, 256, 0, stream>>>(h, eps, off2, sbuf, xb, HALF_NODES);
    }

    // 4. fused 2-layer MLP + BN stats (128-row / 512-thread tile)
    size_t gemm_lds = 69632;
    mlp_fused_kernel<<<(NN + 127) / 128, 512, gemm_lds, stream>>>(
        xb, W1t, W2t, b1, b2, xb, stats);

    // 5. out = h + relu(BN(y2))
    bn_final_kernel<<<BN_BLOCKS, 256, 0, stream>>>(xb, h, gamma, beta, stats, out);
}

// Round 11
// 269.284 us; speedup vs baseline: 2.2388x; 1.0736x over previous
//
#include <hip/hip_runtime.h>

#define NN 100000
#define NE 1600000
#define DD 128
#define BN_EPS 1e-5f

#define SBSH 9                         // log2(super-bucket size)
#define SBSZ 512                       // nodes per super-bucket
#define NSB ((NN + SBSZ - 1) / SBSZ)   // 196 super-buckets
#define CAPS 9216                      // slots per bucket (mean 8163 + ~11 sigma)
#define SCATBLKS 512                   // scatter-role blocks (was 196 -> tail was 1 wave/SIMD)
#define EPB ((NE + SCATBLKS - 1) / SCATBLKS)   // 3125 edges/block; chunk ~16 ints = 1 line
#define PREPBLKS 512
#define GRID_PS (SCATBLKS + PREPBLKS)  // 1024
#define BN_BLOCKS 1024

typedef __attribute__((ext_vector_type(8))) short short8;
typedef __attribute__((ext_vector_type(4))) float floatx4;

__device__ __forceinline__ unsigned short f2bf(float f) {
    union { float f; unsigned u; } v; v.f = f;
    return (unsigned short)((v.u + 0x7FFFu + ((v.u >> 16) & 1u)) >> 16);
}
__device__ __forceinline__ float bf2f(unsigned short u) {
    union { unsigned u; float f; } v; v.u = ((unsigned)u) << 16;
    return v.f;
}

// ---------------------------------------------------------------------------
// K1 (fused): blocks [0,512) = super-bucket radix scatter (chunk-reserved
// direct scatter; ~16-int = 1-line chunks); blocks [512,1024) = prep
// (W->bf16 transpose + h->bf16 copy). R10 counters showed the old 196-block
// scatter ran its tail at 1 wave/SIMD (occ 14%, VALU 3%) -- 512 blocks give
// the latency-bound chain 2.6x the TLP and overlap with prep throughout.
// scnt zeroed by preceding memset.
// ---------------------------------------------------------------------------
__global__ __launch_bounds__(256) void prep_scatter_kernel(
    const float* __restrict__ W1, const float* __restrict__ W2,
    unsigned short* __restrict__ W1t, unsigned short* __restrict__ W2t,
    const float* __restrict__ h, unsigned short* __restrict__ hb, int do_hb,
    const int* __restrict__ src, const int* __restrict__ dst,
    int* __restrict__ scnt, int* __restrict__ sbuf)
{
    __shared__ int bins[256];
    int t = threadIdx.x;

    if (blockIdx.x < SCATBLKS) {
        bins[t] = 0;
        __syncthreads();
        int base = blockIdx.x * EPB;
        int ecnt = min(EPB, NE - base);
        for (int i = t; i < ecnt; i += 256)
            atomicAdd(&bins[dst[base + i] >> SBSH], 1);
        __syncthreads();
        int c = bins[t];
        int gb = (t < NSB && c) ? atomicAdd(&scnt[t], c) : 0;
        __syncthreads();
        bins[t] = t * CAPS + gb;   // global chunk cursor for this block
        __syncthreads();
        for (int i = t; i < ecnt; i += 256) {
            int d = dst[base + i];
            int p = atomicAdd(&bins[d >> SBSH], 1);
            sbuf[p] = (src[base + i] << SBSH) | (d & (SBSZ - 1));
        }
    } else {
        int tid0 = (blockIdx.x - SCATBLKS) * 256 + t;
        int stride = PREPBLKS * 256;
        for (int i = tid0; i < DD * DD; i += stride) {
            int n = i >> 7, k = i & 127;
            W1t[i] = f2bf(W1[k * DD + n]);
            W2t[i] = f2bf(W2[k * DD + n]);
        }
        if (do_hb) {
            const float4* h4 = (const float4*)h;
            ushort4* hb4 = (ushort4*)hb;
            for (int i = tid0; i < NN * (DD / 4); i += stride) {
                float4 v = h4[i];
                ushort4 o;
                o.x = f2bf(v.x); o.y = f2bf(v.y); o.z = f2bf(v.z); o.w = f2bf(v.w);
                hb4[i] = o;
            }
        }
    }
}

// ---------------------------------------------------------------------------
// K2: per-super-bucket CSR permute, now 1024 threads/block (16 waves/CU on
// the 196 occupied CUs -- double the old TLP for the same single-writer
// in-place permute). LDS ~45KB.
// ---------------------------------------------------------------------------
__global__ __launch_bounds__(1024) void permute_kernel(
    const int* __restrict__ scnt, int* __restrict__ sbuf,
    int2* __restrict__ off2)
{
    __shared__ int ew[CAPS];          // 36864 B
    __shared__ int cnt[SBSZ];
    __shared__ int cur[SBSZ];
    __shared__ int stmp[SBSZ];
    int sb = blockIdx.x, t = threadIdx.x;
    if (t < SBSZ) cnt[t] = 0;
    __syncthreads();
    int n = min(scnt[sb], CAPS);
    int sbase = sb * CAPS;
    for (int i = t; i < n; i += 1024) {
        int e = sbuf[sbase + i];
        ew[i] = e;
        atomicAdd(&cnt[e & (SBSZ - 1)], 1);
    }
    __syncthreads();
    int c = 0;
    if (t < SBSZ) { c = cnt[t]; stmp[t] = c; }
    __syncthreads();
#pragma unroll
    for (int ofs = 1; ofs < SBSZ; ofs <<= 1) {
        int u = (t < SBSZ && t >= ofs) ? stmp[t - ofs] : 0;
        __syncthreads();
        if (t < SBSZ) stmp[t] += u;
        __syncthreads();
    }
    if (t < SBSZ) {
        int excl = stmp[t] - c;
        cur[t] = excl;
        off2[sb * SBSZ + t] = make_int2(sbase + excl, sbase + excl + c);
    }
    __syncthreads();
    for (int i = t; i < n; i += 1024) {
        int e = ew[i];
        int p = atomicAdd(&cur[e & (SBSZ - 1)], 1);
        sbuf[sbase + p] = e >> SBSH;   // in place (staged in LDS)
    }
}

// ---------------------------------------------------------------------------
// K3: gather (proven 64us config: 16 lanes/node, unroll-4, no LDS, single
// dispatch again -- attribution split removed).
// ---------------------------------------------------------------------------
__global__ __launch_bounds__(256) void gather_bf16_kernel(
    const float* __restrict__ h, const unsigned short* __restrict__ hb,
    const float* __restrict__ eps, const int2* __restrict__ off2,
    const int* __restrict__ srcs, unsigned short* __restrict__ xb)
{
    int node = blockIdx.x * 16 + (threadIdx.x >> 4);
    if (node >= NN) return;
    int c8 = threadIdx.x & 15;
    const float s = 1.0f + eps[0];
    const float4* h4 = (const float4*)h;
    float4 a0 = h4[node * 32 + c8 * 2];
    float4 a1 = h4[node * 32 + c8 * 2 + 1];
    float acc[8] = {s * a0.x, s * a0.y, s * a0.z, s * a0.w,
                    s * a1.x, s * a1.y, s * a1.z, s * a1.w};
    int2 oo = off2[node];
    int e = oo.x, eend = oo.y;
    const short8* hb8 = (const short8*)hb;
    for (; e + 3 < eend; e += 4) {
        int s0 = srcs[e],     s1 = srcs[e + 1];
        int s2 = srcs[e + 2], s3 = srcs[e + 3];
        short8 v0 = hb8[s0 * 16 + c8];
        short8 v1 = hb8[s1 * 16 + c8];
        short8 v2 = hb8[s2 * 16 + c8];
        short8 v3 = hb8[s3 * 16 + c8];
#pragma unroll
        for (int j = 0; j < 8; ++j) {
            float t0 = bf2f((unsigned short)v0[j]) + bf2f((unsigned short)v1[j]);
            float t1 = bf2f((unsigned short)v2[j]) + bf2f((unsigned short)v3[j]);
            acc[j] += t0 + t1;
        }
    }
    for (; e < eend; ++e) {
        short8 v0 = hb8[srcs[e] * 16 + c8];
#pragma unroll
        for (int j = 0; j < 8; ++j) acc[j] += bf2f((unsigned short)v0[j]);
    }
    short8 o;
#pragma unroll
    for (int j = 0; j < 8; ++j) o[j] = (short)f2bf(acc[j]);
    ((short8*)xb)[node * 16 + c8] = o;
}

__global__ __launch_bounds__(256) void gather_f32_kernel(
    const float* __restrict__ h, const float* __restrict__ eps,
    const int2* __restrict__ off2, const int* __restrict__ srcs,
    unsigned short* __restrict__ xb)
{
    int node = blockIdx.x * 16 + (threadIdx.x >> 4);
    if (node >= NN) return;
    int c8 = threadIdx.x & 15;
    const float4* h4 = (const float4*)h;
    const float s = 1.0f + eps[0];
    float4 a0 = h4[node * 32 + c8 * 2];
    float4 a1 = h4[node * 32 + c8 * 2 + 1];
    float acc[8] = {s * a0.x, s * a0.y, s * a0.z, s * a0.w,
                    s * a1.x, s * a1.y, s * a1.z, s * a1.w};
    int2 oo = off2[node];
    int e = oo.x, eend = oo.y;
    for (; e + 1 < eend; e += 2) {
        int s0 = srcs[e], s1 = srcs[e + 1];
        float4 u0 = h4[s0 * 32 + c8 * 2], u1 = h4[s0 * 32 + c8 * 2 + 1];
        float4 w0 = h4[s1 * 32 + c8 * 2], w1 = h4[s1 * 32 + c8 * 2 + 1];
        acc[0] += u0.x + w0.x; acc[1] += u0.y + w0.y;
        acc[2] += u0.z + w0.z; acc[3] += u0.w + w0.w;
        acc[4] += u1.x + w1.x; acc[5] += u1.y + w1.y;
        acc[6] += u1.z + w1.z; acc[7] += u1.w + w1.w;
    }
    if (e < eend) {
        int s0 = srcs[e];
        float4 u0 = h4[s0 * 32 + c8 * 2], u1 = h4[s0 * 32 + c8 * 2 + 1];
        acc[0] += u0.x; acc[1] += u0.y; acc[2] += u0.z; acc[3] += u0.w;
        acc[4] += u1.x; acc[5] += u1.y; acc[6] += u1.z; acc[7] += u1.w;
    }
    short8 o;
#pragma unroll
    for (int j = 0; j < 8; ++j) o[j] = (short)f2bf(acc[j]);
    ((short8*)xb)[node * 16 + c8] = o;
}

// ---------------------------------------------------------------------------
// K4: fused 2-layer MLP + BN stats, 128-row / 512-thread tile (R10-proven,
// e2e -15us vs 64-row). W staged once per layer per 128 rows.
// ---------------------------------------------------------------------------
__global__ __launch_bounds__(512) void mlp_fused_kernel(
    const unsigned short* __restrict__ X,
    const unsigned short* __restrict__ W1t, const unsigned short* __restrict__ W2t,
    const float* __restrict__ b1, const float* __restrict__ b2,
    unsigned short* __restrict__ Y, float* __restrict__ stats)
{
    extern __shared__ char smem[];
    unsigned short* wl = (unsigned short*)smem;            // [128][136] bf16
    unsigned short* xl = (unsigned short*)(smem + 34816);  // [128][136] bf16

    const int tid = threadIdx.x;
    const int r0 = blockIdx.x * 128;
    const int lane = tid & 63;
    const int wv = tid >> 6;        // 0..7: wave's 16-row band
    const int m = lane & 15;
    const int hi = lane >> 4;

    const short8* W18 = (const short8*)W1t;
#pragma unroll
    for (int l = 0; l < 4; ++l) {
        int idx = tid + l * 512;
        int n = idx >> 4, c = idx & 15;
        *(short8*)&wl[n * 136 + c * 8] = W18[idx];
    }
    const short8* X8 = (const short8*)X;
#pragma unroll
    for (int l = 0; l < 4; ++l) {
        int idx = tid + l * 512;
        int row = idx >> 4, c = idx & 15;
        int g = r0 + row;
        short8 v = {0, 0, 0, 0, 0, 0, 0, 0};
        if (g < NN) v = X8[g * 16 + c];
        *(short8*)&xl[row * 136 + c * 8] = v;
    }
    __syncthreads();

    floatx4 acc[8];
#pragma unroll
    for (int i = 0; i < 8; ++i) acc[i] = (floatx4){0.f, 0.f, 0.f, 0.f};
#pragma unroll
    for (int kc = 0; kc < 4; ++kc) {
        short8 a = *(const short8*)&xl[(wv * 16 + m) * 136 + kc * 32 + hi * 8];
#pragma unroll
        for (int nt = 0; nt < 8; ++nt) {
            short8 b = *(const short8*)&wl[(nt * 16 + m) * 136 + kc * 32 + hi * 8];
            acc[nt] = __builtin_amdgcn_mfma_f32_16x16x32_bf16(a, b, acc[nt], 0, 0, 0);
        }
    }
    __syncthreads();

#pragma unroll
    for (int nt = 0; nt < 8; ++nt) {
        float bv = b1[nt * 16 + m];
#pragma unroll
        for (int r = 0; r < 4; ++r) {
            float v = fmaxf(acc[nt][r] + bv, 0.f);
            xl[(wv * 16 + hi * 4 + r) * 136 + nt * 16 + m] = f2bf(v);
        }
    }
    const short8* W28 = (const short8*)W2t;
#pragma unroll
    for (int l = 0; l < 4; ++l) {
        int idx = tid + l * 512;
        int n = idx >> 4, c = idx & 15;
        *(short8*)&wl[n * 136 + c * 8] = W28[idx];
    }
    __syncthreads();

#pragma unroll
    for (int i = 0; i < 8; ++i) acc[i] = (floatx4){0.f, 0.f, 0.f, 0.f};
#pragma unroll
    for (int kc = 0; kc < 4; ++kc) {
        short8 a = *(const short8*)&xl[(wv * 16 + m) * 136 + kc * 32 + hi * 8];
#pragma unroll
        for (int nt = 0; nt < 8; ++nt) {
            short8 b = *(const short8*)&wl[(nt * 16 + m) * 136 + kc * 32 + hi * 8];
            acc[nt] = __builtin_amdgcn_mfma_f32_16x16x32_bf16(a, b, acc[nt], 0, 0, 0);
        }
    }
    __syncthreads();

#pragma unroll
    for (int nt = 0; nt < 8; ++nt) {
        float bv = b2[nt * 16 + m];
#pragma unroll
        for (int r = 0; r < 4; ++r) {
            float v = acc[nt][r] + bv;
            xl[(wv * 16 + hi * 4 + r) * 136 + nt * 16 + m] = f2bf(v);
        }
    }
    __syncthreads();

#pragma unroll
    for (int l = 0; l < 4; ++l) {
        int idx = tid + l * 512;
        int row = idx >> 4, c = idx & 15;
        int g = r0 + row;
        if (g < NN)
            ((short8*)Y)[g * 16 + c] = *(const short8*)&xl[row * 136 + c * 8];
    }

    int col = tid & 127, quarter = tid >> 7;
    int rlim = min(128, NN - r0);
    int rbeg = quarter * 32, rend = min(rbeg + 32, rlim);
    float s = 0.f, q = 0.f;
    for (int r = rbeg; r < rend; ++r) {
        float v = bf2f(xl[r * 136 + col]);
        s += v; q += v * v;
    }
    float* red = (float*)wl;        // wl dead after GEMM2
    red[tid] = s;
    red[512 + tid] = q;
    __syncthreads();
    if (tid < 128) {
        float ts = red[tid] + red[128 + tid] + red[256 + tid] + red[384 + tid];
        float tq = red[512 + tid] + red[640 + tid] + red[768 + tid] + red[896 + tid];
        atomicAdd(&stats[tid], ts);
        atomicAdd(&stats[DD + tid], tq);
    }
}

// ---------------------------------------------------------------------------
// K5: out = h + relu(Y*scale + shift). BN math hoisted (column octet fixed).
// ---------------------------------------------------------------------------
__global__ __launch_bounds__(256) void bn_final_kernel(
    const unsigned short* __restrict__ Y, const float* __restrict__ h,
    const float* __restrict__ gamma, const float* __restrict__ beta,
    const float* __restrict__ stats, float* __restrict__ out)
{
    const float invN = 1.0f / (float)NN;
    int t0 = blockIdx.x * 256 + threadIdx.x;
    int c8 = t0 & 15;
    float sc[8], sh[8];
#pragma unroll
    for (int j = 0; j < 8; ++j) {
        int col = c8 * 8 + j;
        float mu = stats[col] * invN;
        float var = stats[DD + col] * invN - mu * mu;
        float s = rsqrtf(var + BN_EPS) * gamma[col];
        sc[j] = s;
        sh[j] = beta[col] - mu * s;
    }
    const short8* Y8 = (const short8*)Y;
    const float4* H4 = (const float4*)h;
    float4* O4 = (float4*)out;
    const int total = NN * 16;
    const int stride = BN_BLOCKS * 256;
    for (int i = t0; i < total; i += stride) {
        short8 u = Y8[i];
        float4 h0 = H4[2 * i], h1 = H4[2 * i + 1];
        float4 r0, r1;
        r0.x = h0.x + fmaxf(bf2f((unsigned short)u[0]) * sc[0] + sh[0], 0.f);
        r0.y = h0.y + fmaxf(bf2f((unsigned short)u[1]) * sc[1] + sh[1], 0.f);
        r0.z = h0.z + fmaxf(bf2f((unsigned short)u[2]) * sc[2] + sh[2], 0.f);
        r0.w = h0.w + fmaxf(bf2f((unsigned short)u[3]) * sc[3] + sh[3], 0.f);
        r1.x = h1.x + fmaxf(bf2f((unsigned short)u[4]) * sc[4] + sh[4], 0.f);
        r1.y = h1.y + fmaxf(bf2f((unsigned short)u[5]) * sc[5] + sh[5], 0.f);
        r1.z = h1.z + fmaxf(bf2f((unsigned short)u[6]) * sc[6] + sh[6], 0.f);
        r1.w = h1.w + fmaxf(bf2f((unsigned short)u[7]) * sc[7] + sh[7], 0.f);
        O4[2 * i] = r0;
        O4[2 * i + 1] = r1;
    }
}

// ---------------------------------------------------------------------------
extern "C" void kernel_launch(void* const* d_in, const int* in_sizes, int n_in,
                              void* d_out, int out_size, void* d_ws, size_t ws_size,
                              hipStream_t stream)
{
    const float* h     = (const float*)d_in[0];
    const int*   src   = (const int*)d_in[1];
    const int*   dst   = (const int*)d_in[2];
    const float* eps   = (const float*)d_in[3];
    const float* W1    = (const float*)d_in[4];
    const float* b1    = (const float*)d_in[5];
    const float* W2    = (const float*)d_in[6];
    const float* b2    = (const float*)d_in[7];
    const float* gamma = (const float*)d_in[8];
    const float* beta  = (const float*)d_in[9];
    float* out = (float*)d_out;

    char* w = (char*)d_ws;
    size_t o = 0;
    float* stats    = (float*)(w + o); o += 256 * 4;                 // memset
    int* scnt       = (int*)(w + o); o += 256 * 4;                   // memset
    unsigned short* W1t = (unsigned short*)(w + o); o += (size_t)DD * DD * 2;
    unsigned short* W2t = (unsigned short*)(w + o); o += (size_t)DD * DD * 2;
    int2* off2      = (int2*)(w + o); o += (size_t)NSB * SBSZ * 8;   // 802816
    int* sbuf       = (int*)(w + o); o += (size_t)NSB * CAPS * 4;    // 7.2 MB
    unsigned short* xb  = (unsigned short*)(w + o); o += (size_t)NN * DD * 2;
    unsigned short* hb  = (unsigned short*)(w + o); o += (size_t)NN * DD * 2;
    const int use_hb = (ws_size >= o) ? 1 : 0;  // launch-constant

    // 0. zero stats + super-bucket cursors
    hipMemsetAsync(stats, 0, 512 * sizeof(int), stream);

    // 1. fused prep + radix scatter (512 scatter + 512 prep blocks)
    prep_scatter_kernel<<<GRID_PS, 256, 0, stream>>>(
        W1, W2, W1t, W2t, h, hb, use_hb, src, dst, scnt, sbuf);

    // 2. per-super-bucket CSR permute (1024 threads/block)
    permute_kernel<<<NSB, 1024, 0, stream>>>(scnt, sbuf, off2);

    // 3. gather (single dispatch)
    if (use_hb)
        gather_bf16_kernel<<<(NN + 15) / 16, 256, 0, stream>>>(h, hb, eps, off2, sbuf, xb);
    else
        gather_f32_kernel<<<(NN + 15) / 16, 256, 0, stream>>>(h, eps, off2, sbuf, xb);

    // 4. fused 2-layer MLP + BN stats (128-row / 512-thread tile)
    size_t gemm_lds = 69632;
    mlp_fused_kernel<<<(NN + 127) / 128, 512, gemm_lds, stream>>>(
        xb, W1t, W2t, b1, b2, xb, stats);

    // 5. out = h + relu(BN(y2))
    bn_final_kernel<<<BN_BLOCKS, 256, 0, stream>>>(xb, h, gamma, beta, stats, out);
}